// Round 1
// baseline (7863.892 us; speedup 1.0000x reference)
//
#include <hip/hip_runtime.h>
#include <math.h>

#define B 8
#define N 10000
#define D 16
#define E 320000
#define EH 32
#define EOUT 30
#define NOUT 64
#define FEAT 35   // 2*D + 2 + 1

__device__ __forceinline__ float sigmoidf_(float v) {
    return 1.0f / (1.0f + __expf(-v));
}

// ---------------------------------------------------------------------------
// Stage 1: column-wise sum / sumsq of edge_attr (E x 2) for mean/std(ddof=1)
// stats[0]=sum_d, stats[1]=sum_a, stats[2]=sumsq_d, stats[3]=sumsq_a
// ---------------------------------------------------------------------------
__global__ void stats_kernel(const float* __restrict__ ea, float* __restrict__ stats) {
    float s0 = 0.f, s1 = 0.f, q0 = 0.f, q1 = 0.f;
    for (int i = blockIdx.x * blockDim.x + threadIdx.x; i < E; i += gridDim.x * blockDim.x) {
        float2 v = *(const float2*)(ea + 2 * (size_t)i);
        s0 += v.x; q0 += v.x * v.x;
        s1 += v.y; q1 += v.y * v.y;
    }
    #pragma unroll
    for (int off = 32; off > 0; off >>= 1) {
        s0 += __shfl_down(s0, off);
        s1 += __shfl_down(s1, off);
        q0 += __shfl_down(q0, off);
        q1 += __shfl_down(q1, off);
    }
    if ((threadIdx.x & 63) == 0) {
        atomicAdd(&stats[0], s0);
        atomicAdd(&stats[1], s1);
        atomicAdd(&stats[2], q0);
        atomicAdd(&stats[3], q1);
    }
}

// stats[4]=mean_d, stats[5]=inv_std_d, stats[6]=mean_a, stats[7]=inv_std_a
__global__ void finalize_kernel(float* __restrict__ stats) {
    if (threadIdx.x == 0 && blockIdx.x == 0) {
        const float n = (float)E;
        float s0 = stats[0], s1 = stats[1], q0 = stats[2], q1 = stats[3];
        float m0 = s0 / n, m1 = s1 / n;
        float v0 = (q0 - s0 * s0 / n) / (n - 1.0f);
        float v1 = (q1 - s1 * s1 / n) / (n - 1.0f);
        stats[4] = m0;
        stats[5] = 1.0f / sqrtf(v0);
        stats[6] = m1;
        stats[7] = 1.0f / sqrtf(v1);
    }
}

// ---------------------------------------------------------------------------
// Stage 2: per-(batch, edge) MLP + scatter with atomics.
// feat = [x_src(16), x_tgt(16), ea_norm(2), edge_weight(1)]  -> 35
// h = sigmoid(feat @ W1 + b1)   (35->32)
// e = sigmoid(h @ W2 + b2)      (32->30)
// agg[b, tgt] += e ; agg[b, src] -= e
// ---------------------------------------------------------------------------
__global__ void __launch_bounds__(256) edge_kernel(
    const float* __restrict__ x, const int* __restrict__ eidx,
    const float* __restrict__ ea,
    const float* __restrict__ wind_mean, const float* __restrict__ wind_std,
    const float* __restrict__ W1, const float* __restrict__ b1,
    const float* __restrict__ W2, const float* __restrict__ b2,
    const float* __restrict__ stats, float* __restrict__ agg)
{
    int t = blockIdx.x * blockDim.x + threadIdx.x;
    if (t >= B * E) return;
    int b = t / E;
    int e = t - b * E;

    int src = eidx[e];
    int tgt = eidx[E + e];

    const float* xs = x + ((size_t)b * N + src) * D;
    const float* xt = x + ((size_t)b * N + tgt) * D;

    float f[FEAT];
    {
        float4 a0 = *(const float4*)(xs + 0);
        float4 a1 = *(const float4*)(xs + 4);
        float4 a2 = *(const float4*)(xs + 8);
        float4 a3 = *(const float4*)(xs + 12);
        f[0] = a0.x; f[1] = a0.y; f[2] = a0.z; f[3] = a0.w;
        f[4] = a1.x; f[5] = a1.y; f[6] = a1.z; f[7] = a1.w;
        f[8] = a2.x; f[9] = a2.y; f[10] = a2.z; f[11] = a2.w;
        f[12] = a3.x; f[13] = a3.y; f[14] = a3.z; f[15] = a3.w;
        float4 c0 = *(const float4*)(xt + 0);
        float4 c1 = *(const float4*)(xt + 4);
        float4 c2 = *(const float4*)(xt + 8);
        float4 c3 = *(const float4*)(xt + 12);
        f[16] = c0.x; f[17] = c0.y; f[18] = c0.z; f[19] = c0.w;
        f[20] = c1.x; f[21] = c1.y; f[22] = c1.z; f[23] = c1.w;
        f[24] = c2.x; f[25] = c2.y; f[26] = c2.z; f[27] = c2.w;
        f[28] = c3.x; f[29] = c3.y; f[30] = c3.z; f[31] = c3.w;
    }

    float2 eav = *(const float2*)(ea + 2 * (size_t)e);
    float dist = eav.x, cdir = eav.y;

    f[32] = (dist - stats[4]) * stats[5];
    f[33] = (cdir - stats[6]) * stats[7];

    float speed = f[14] * wind_std[0] + wind_mean[0];
    float sdir  = f[15] * wind_std[1] + wind_mean[1];
    float theta = fabsf(cdir - sdir);
    float ew = 3.0f * speed * cosf(theta) / dist;
    f[34] = fmaxf(ew, 0.0f);

    // ---- layer 1: 35 -> 32 ----
    float h[EH];
    #pragma unroll
    for (int j = 0; j < EH; j++) h[j] = b1[j];
    #pragma unroll
    for (int k = 0; k < FEAT; k++) {
        float fk = f[k];
        #pragma unroll
        for (int j = 0; j < EH; j++)
            h[j] = fmaf(fk, W1[k * EH + j], h[j]);
    }
    #pragma unroll
    for (int j = 0; j < EH; j++) h[j] = sigmoidf_(h[j]);

    // ---- layer 2: 32 -> 30 ----
    float o[EOUT];
    #pragma unroll
    for (int j = 0; j < EOUT; j++) o[j] = b2[j];
    #pragma unroll
    for (int k = 0; k < EH; k++) {
        float hk = h[k];
        #pragma unroll
        for (int j = 0; j < EOUT; j++)
            o[j] = fmaf(hk, W2[k * EOUT + j], o[j]);
    }
    #pragma unroll
    for (int j = 0; j < EOUT; j++) o[j] = sigmoidf_(o[j]);

    // ---- scatter ----
    float* at = agg + ((size_t)b * N + tgt) * EOUT;
    float* as = agg + ((size_t)b * N + src) * EOUT;
    #pragma unroll
    for (int j = 0; j < EOUT; j++) {
        atomicAdd(at + j,  o[j]);
        atomicAdd(as + j, -o[j]);
    }
}

// ---------------------------------------------------------------------------
// Stage 3: out = sigmoid(agg @ Wn + bn)   (30 -> 64), thread per output elem.
// One wave (64 lanes) covers exactly one row's 64 outputs -> agg reads are
// wave-uniform broadcasts, Wn reads are coalesced.
// ---------------------------------------------------------------------------
__global__ void __launch_bounds__(256) node_kernel(
    const float* __restrict__ agg, const float* __restrict__ Wn,
    const float* __restrict__ bn, float* __restrict__ out)
{
    int t = blockIdx.x * blockDim.x + threadIdx.x;
    if (t >= B * N * NOUT) return;
    int row = t >> 6;       // / 64
    int j   = t & 63;
    const float* a = agg + (size_t)row * EOUT;
    float acc = bn[j];
    #pragma unroll
    for (int k = 0; k < EOUT; k++)
        acc = fmaf(a[k], Wn[k * NOUT + j], acc);
    out[t] = sigmoidf_(acc);
}

extern "C" void kernel_launch(void* const* d_in, const int* in_sizes, int n_in,
                              void* d_out, int out_size, void* d_ws, size_t ws_size,
                              hipStream_t stream) {
    const float* x         = (const float*)d_in[0];
    const int*   eidx      = (const int*)d_in[1];
    const float* ea        = (const float*)d_in[2];
    const float* wind_mean = (const float*)d_in[3];
    const float* wind_std  = (const float*)d_in[4];
    const float* W1        = (const float*)d_in[5];
    const float* b1        = (const float*)d_in[6];
    const float* W2        = (const float*)d_in[7];
    const float* b2        = (const float*)d_in[8];
    const float* Wn        = (const float*)d_in[9];
    const float* bn        = (const float*)d_in[10];
    float* out = (float*)d_out;

    float* stats = (float*)d_ws;
    float* agg   = (float*)d_ws + 16;   // 64-byte offset

    // zero stats (32 B) + agg (B*N*EOUT floats)
    size_t zero_bytes = 64 + (size_t)B * N * EOUT * sizeof(float);
    hipMemsetAsync(d_ws, 0, zero_bytes, stream);

    stats_kernel<<<256, 256, 0, stream>>>(ea, stats);
    finalize_kernel<<<1, 64, 0, stream>>>(stats);

    int nwork = B * E;
    edge_kernel<<<(nwork + 255) / 256, 256, 0, stream>>>(
        x, eidx, ea, wind_mean, wind_std, W1, b1, W2, b2, stats, agg);

    int nout_elems = B * N * NOUT;
    node_kernel<<<(nout_elems + 255) / 256, 256, 0, stream>>>(agg, Wn, bn, out);
}

// Round 2
// 621.669 us; speedup vs baseline: 12.6496x; 12.6496x over previous
//
#include <hip/hip_runtime.h>
#include <math.h>

#define B 8
#define N 10000
#define D 16
#define E 320000
#define EH 32
#define EOUT 30
#define NOUT 64
#define FEAT 35   // 2*D + 2 + 1
#define EPAD 32   // padded e-row stride (128 B)

__device__ __forceinline__ float sigmoidf_(float v) {
    return 1.0f / (1.0f + __expf(-v));
}

// ---------------------------------------------------------------------------
// edge_attr column stats (mean / std ddof=1)
// stats[0..3]=sums/sumsq, stats[4..7]=mean_d,invstd_d,mean_a,invstd_a
// ---------------------------------------------------------------------------
__global__ void stats_kernel(const float* __restrict__ ea, float* __restrict__ stats) {
    float s0 = 0.f, s1 = 0.f, q0 = 0.f, q1 = 0.f;
    for (int i = blockIdx.x * blockDim.x + threadIdx.x; i < E; i += gridDim.x * blockDim.x) {
        float2 v = *(const float2*)(ea + 2 * (size_t)i);
        s0 += v.x; q0 += v.x * v.x;
        s1 += v.y; q1 += v.y * v.y;
    }
    #pragma unroll
    for (int off = 32; off > 0; off >>= 1) {
        s0 += __shfl_down(s0, off);
        s1 += __shfl_down(s1, off);
        q0 += __shfl_down(q0, off);
        q1 += __shfl_down(q1, off);
    }
    if ((threadIdx.x & 63) == 0) {
        atomicAdd(&stats[0], s0);
        atomicAdd(&stats[1], s1);
        atomicAdd(&stats[2], q0);
        atomicAdd(&stats[3], q1);
    }
}

__global__ void finalize_kernel(float* __restrict__ stats) {
    if (threadIdx.x == 0 && blockIdx.x == 0) {
        const float n = (float)E;
        float s0 = stats[0], s1 = stats[1], q0 = stats[2], q1 = stats[3];
        float v0 = (q0 - s0 * s0 / n) / (n - 1.0f);
        float v1 = (q1 - s1 * s1 / n) / (n - 1.0f);
        stats[4] = s0 / n;
        stats[5] = 1.0f / sqrtf(v0);
        stats[6] = s1 / n;
        stats[7] = 1.0f / sqrtf(v1);
    }
}

// ---------------------------------------------------------------------------
// CSR binning: count -> scan -> fill
// slots [0,N): node as tgt (add);  [N,2N): node as src (subtract)
// ---------------------------------------------------------------------------
__global__ void count_kernel(const int* __restrict__ eidx, int* __restrict__ cnt) {
    int e = blockIdx.x * blockDim.x + threadIdx.x;
    if (e >= E) return;
    int src = eidx[e];
    int tgt = eidx[E + e];
    atomicAdd(&cnt[tgt], 1);
    atomicAdd(&cnt[N + src], 1);
}

// single block, 1024 threads: exclusive scan of cnt[2N] -> offs[2N+1], cursor
// (cursor may alias cnt: all reads happen before the first barrier)
__global__ void __launch_bounds__(1024) scan_kernel(const int* __restrict__ cnt_in,
                                                    int* __restrict__ offs,
                                                    int* __restrict__ cursor) {
    const int M = 2 * N;         // 20000
    const int CH = 20;           // 1024*20 >= 20000
    __shared__ int lds[1024];
    int t = threadIdx.x;
    int base = t * CH;
    int loc[CH];
    int s = 0;
    #pragma unroll
    for (int i = 0; i < CH; i++) {
        int idx = base + i;
        int v = (idx < M) ? cnt_in[idx] : 0;
        loc[i] = s;
        s += v;
    }
    lds[t] = s;
    __syncthreads();
    for (int off = 1; off < 1024; off <<= 1) {
        int v = (t >= off) ? lds[t - off] : 0;
        __syncthreads();
        lds[t] += v;
        __syncthreads();
    }
    int tbase = (t > 0) ? lds[t - 1] : 0;
    #pragma unroll
    for (int i = 0; i < CH; i++) {
        int idx = base + i;
        if (idx < M) {
            offs[idx] = tbase + loc[i];
            cursor[idx] = tbase + loc[i];
        }
    }
    if (t == 1023) offs[M] = lds[1023];
}

__global__ void fill_kernel(const int* __restrict__ eidx, int* __restrict__ cursor,
                            int* __restrict__ lists) {
    int e = blockIdx.x * blockDim.x + threadIdx.x;
    if (e >= E) return;
    int src = eidx[e];
    int tgt = eidx[E + e];
    int p = atomicAdd(&cursor[tgt], 1);
    lists[p] = e;
    int q = atomicAdd(&cursor[N + src], 1);
    lists[q] = e;
}

// ---------------------------------------------------------------------------
// Edge MLP (no scatter): e_vec per (batch,edge), stored as padded 128B rows
// ---------------------------------------------------------------------------
__global__ void __launch_bounds__(256) edge_mlp_kernel(
    const float* __restrict__ x, const int* __restrict__ eidx,
    const float* __restrict__ ea,
    const float* __restrict__ wind_mean, const float* __restrict__ wind_std,
    const float* __restrict__ W1, const float* __restrict__ b1,
    const float* __restrict__ W2, const float* __restrict__ b2,
    const float* __restrict__ stats, float* __restrict__ eBuf,
    int b0, int nb)
{
    int t = blockIdx.x * blockDim.x + threadIdx.x;
    if (t >= nb * E) return;
    int bb = t / E;          // chunk-local batch
    int e = t - bb * E;
    int b = b0 + bb;

    int src = eidx[e];
    int tgt = eidx[E + e];

    const float* xs = x + ((size_t)b * N + src) * D;
    const float* xt = x + ((size_t)b * N + tgt) * D;

    float f[FEAT];
    {
        float4 a0 = *(const float4*)(xs + 0);
        float4 a1 = *(const float4*)(xs + 4);
        float4 a2 = *(const float4*)(xs + 8);
        float4 a3 = *(const float4*)(xs + 12);
        f[0] = a0.x; f[1] = a0.y; f[2] = a0.z; f[3] = a0.w;
        f[4] = a1.x; f[5] = a1.y; f[6] = a1.z; f[7] = a1.w;
        f[8] = a2.x; f[9] = a2.y; f[10] = a2.z; f[11] = a2.w;
        f[12] = a3.x; f[13] = a3.y; f[14] = a3.z; f[15] = a3.w;
        float4 c0 = *(const float4*)(xt + 0);
        float4 c1 = *(const float4*)(xt + 4);
        float4 c2 = *(const float4*)(xt + 8);
        float4 c3 = *(const float4*)(xt + 12);
        f[16] = c0.x; f[17] = c0.y; f[18] = c0.z; f[19] = c0.w;
        f[20] = c1.x; f[21] = c1.y; f[22] = c1.z; f[23] = c1.w;
        f[24] = c2.x; f[25] = c2.y; f[26] = c2.z; f[27] = c2.w;
        f[28] = c3.x; f[29] = c3.y; f[30] = c3.z; f[31] = c3.w;
    }

    float2 eav = *(const float2*)(ea + 2 * (size_t)e);
    float dist = eav.x, cdir = eav.y;

    f[32] = (dist - stats[4]) * stats[5];
    f[33] = (cdir - stats[6]) * stats[7];

    float speed = f[14] * wind_std[0] + wind_mean[0];
    float sdir  = f[15] * wind_std[1] + wind_mean[1];
    float theta = fabsf(cdir - sdir);
    float ew = 3.0f * speed * cosf(theta) / dist;
    f[34] = fmaxf(ew, 0.0f);

    float h[EH];
    #pragma unroll
    for (int j = 0; j < EH; j++) h[j] = b1[j];
    #pragma unroll
    for (int k = 0; k < FEAT; k++) {
        float fk = f[k];
        #pragma unroll
        for (int j = 0; j < EH; j++)
            h[j] = fmaf(fk, W1[k * EH + j], h[j]);
    }
    #pragma unroll
    for (int j = 0; j < EH; j++) h[j] = sigmoidf_(h[j]);

    float o[EOUT];
    #pragma unroll
    for (int j = 0; j < EOUT; j++) o[j] = b2[j];
    #pragma unroll
    for (int k = 0; k < EH; k++) {
        float hk = h[k];
        #pragma unroll
        for (int j = 0; j < EOUT; j++)
            o[j] = fmaf(hk, W2[k * EOUT + j], o[j]);
    }
    #pragma unroll
    for (int j = 0; j < EOUT; j++) o[j] = sigmoidf_(o[j]);

    float4* row = (float4*)(eBuf + ((size_t)bb * E + e) * EPAD);
    row[0] = make_float4(o[0],  o[1],  o[2],  o[3]);
    row[1] = make_float4(o[4],  o[5],  o[6],  o[7]);
    row[2] = make_float4(o[8],  o[9],  o[10], o[11]);
    row[3] = make_float4(o[12], o[13], o[14], o[15]);
    row[4] = make_float4(o[16], o[17], o[18], o[19]);
    row[5] = make_float4(o[20], o[21], o[22], o[23]);
    row[6] = make_float4(o[24], o[25], o[26], o[27]);
    row[7] = make_float4(o[28], o[29], 0.f,  0.f);
}

// ---------------------------------------------------------------------------
// Fused gather + node MLP: one wave per (batch,node).
// Lanes 0-31 / 32-63 each pull one edge row per iteration (pairs), fold,
// then 30->64 layer via shuffle-broadcast.
// ---------------------------------------------------------------------------
__global__ void __launch_bounds__(256) gather_kernel(
    const float* __restrict__ eBuf, const int* __restrict__ offs,
    const int* __restrict__ lists, const float* __restrict__ Wn,
    const float* __restrict__ bn, float* __restrict__ out,
    int b0, int nb)
{
    int wid = (blockIdx.x * blockDim.x + threadIdx.x) >> 6;
    int lane = threadIdx.x & 63;
    if (wid >= nb * N) return;
    int bb = wid / N;
    int node = wid - bb * N;
    int b = b0 + bb;

    float acc = 0.f;
    int half = lane >> 5;        // 0 for lanes 0-31, 1 for 32-63
    int col = lane & 31;
    const float* ebase = eBuf + (size_t)bb * E * EPAD;

    // in-list: add
    {
        int s = offs[node], eend = offs[node + 1];
        for (int base = s; base < eend; base += 64) {
            int n = eend - base; if (n > 64) n = 64;
            int myeid = (lane < n) ? lists[base + lane] : 0;
            for (int i = 0; i < n; i += 2) {
                int sel = i + half;
                int eid = __shfl(myeid, sel < 64 ? sel : 0);
                float v = (sel < n) ? ebase[(size_t)eid * EPAD + col] : 0.f;
                acc += v;
            }
        }
    }
    // out-list: subtract
    {
        int s = offs[N + node], eend = offs[N + node + 1];
        for (int base = s; base < eend; base += 64) {
            int n = eend - base; if (n > 64) n = 64;
            int myeid = (lane < n) ? lists[base + lane] : 0;
            for (int i = 0; i < n; i += 2) {
                int sel = i + half;
                int eid = __shfl(myeid, sel < 64 ? sel : 0);
                float v = (sel < n) ? ebase[(size_t)eid * EPAD + col] : 0.f;
                acc -= v;
            }
        }
    }

    // fold halves: every lane gets tot = agg[lane&31]
    float tot = acc + __shfl(acc, lane ^ 32);

    // node layer: out[j] = sigmoid(bn[j] + sum_k agg[k]*Wn[k][j]), j = lane
    float o = bn[lane];
    #pragma unroll
    for (int k = 0; k < EOUT; k++) {
        float ak = __shfl(tot, k);
        o = fmaf(ak, Wn[k * NOUT + lane], o);
    }
    out[((size_t)b * N + node) * NOUT + lane] = sigmoidf_(o);
}

// ---------------------------------------------------------------------------
// Fallback (small ws): round-1 atomic path
// ---------------------------------------------------------------------------
__global__ void __launch_bounds__(256) edge_kernel_atomic(
    const float* __restrict__ x, const int* __restrict__ eidx,
    const float* __restrict__ ea,
    const float* __restrict__ wind_mean, const float* __restrict__ wind_std,
    const float* __restrict__ W1, const float* __restrict__ b1,
    const float* __restrict__ W2, const float* __restrict__ b2,
    const float* __restrict__ stats, float* __restrict__ agg)
{
    int t = blockIdx.x * blockDim.x + threadIdx.x;
    if (t >= B * E) return;
    int b = t / E;
    int e = t - b * E;
    int src = eidx[e];
    int tgt = eidx[E + e];
    const float* xs = x + ((size_t)b * N + src) * D;
    const float* xt = x + ((size_t)b * N + tgt) * D;
    float f[FEAT];
    #pragma unroll
    for (int i = 0; i < D; i++) f[i] = xs[i];
    #pragma unroll
    for (int i = 0; i < D; i++) f[D + i] = xt[i];
    float2 eav = *(const float2*)(ea + 2 * (size_t)e);
    f[32] = (eav.x - stats[4]) * stats[5];
    f[33] = (eav.y - stats[6]) * stats[7];
    float speed = f[14] * wind_std[0] + wind_mean[0];
    float sdir  = f[15] * wind_std[1] + wind_mean[1];
    float ew = 3.0f * speed * cosf(fabsf(eav.y - sdir)) / eav.x;
    f[34] = fmaxf(ew, 0.0f);
    float h[EH];
    #pragma unroll
    for (int j = 0; j < EH; j++) h[j] = b1[j];
    #pragma unroll
    for (int k = 0; k < FEAT; k++) {
        float fk = f[k];
        #pragma unroll
        for (int j = 0; j < EH; j++) h[j] = fmaf(fk, W1[k * EH + j], h[j]);
    }
    #pragma unroll
    for (int j = 0; j < EH; j++) h[j] = sigmoidf_(h[j]);
    float o[EOUT];
    #pragma unroll
    for (int j = 0; j < EOUT; j++) o[j] = b2[j];
    #pragma unroll
    for (int k = 0; k < EH; k++) {
        float hk = h[k];
        #pragma unroll
        for (int j = 0; j < EOUT; j++) o[j] = fmaf(hk, W2[k * EOUT + j], o[j]);
    }
    float* at = agg + ((size_t)b * N + tgt) * EOUT;
    float* as = agg + ((size_t)b * N + src) * EOUT;
    #pragma unroll
    for (int j = 0; j < EOUT; j++) {
        float v = sigmoidf_(o[j]);
        atomicAdd(at + j,  v);
        atomicAdd(as + j, -v);
    }
}

__global__ void __launch_bounds__(256) node_kernel_fallback(
    const float* __restrict__ agg, const float* __restrict__ Wn,
    const float* __restrict__ bn, float* __restrict__ out)
{
    int t = blockIdx.x * blockDim.x + threadIdx.x;
    if (t >= B * N * NOUT) return;
    int row = t >> 6;
    int j   = t & 63;
    const float* a = agg + (size_t)row * EOUT;
    float acc = bn[j];
    #pragma unroll
    for (int k = 0; k < EOUT; k++) acc = fmaf(a[k], Wn[k * NOUT + j], acc);
    out[t] = sigmoidf_(acc);
}

// ---------------------------------------------------------------------------
extern "C" void kernel_launch(void* const* d_in, const int* in_sizes, int n_in,
                              void* d_out, int out_size, void* d_ws, size_t ws_size,
                              hipStream_t stream) {
    const float* x         = (const float*)d_in[0];
    const int*   eidx      = (const int*)d_in[1];
    const float* ea        = (const float*)d_in[2];
    const float* wind_mean = (const float*)d_in[3];
    const float* wind_std  = (const float*)d_in[4];
    const float* W1        = (const float*)d_in[5];
    const float* b1        = (const float*)d_in[6];
    const float* W2        = (const float*)d_in[7];
    const float* b2        = (const float*)d_in[8];
    const float* Wn        = (const float*)d_in[9];
    const float* bn        = (const float*)d_in[10];
    float* out = (float*)d_out;

    char* ws = (char*)d_ws;
    // layout (bytes):
    //   stats:  [0, 256)
    //   offs:   [256, 256+80004) -> pad to 80384
    //   cnt:    [80384, 160384) -> pad to 160512   (reused as cursor)
    //   lists:  [160512, 160512+2*E*4) = [160512, 2720512)
    //   eBuf:   [2720512, ...)  chunk * E * EPAD * 4 bytes per batch
    float* stats = (float*)(ws + 0);
    int*   offs  = (int*)(ws + 256);
    int*   cnt   = (int*)(ws + 80384);
    int*   lists = (int*)(ws + 160512);
    float* eBuf  = (float*)(ws + 2720512);
    const size_t fixed = 2720512;
    const size_t perBatch = (size_t)E * EPAD * sizeof(float); // 40,960,000

    if (ws_size >= fixed + perBatch) {
        int chunk = (int)((ws_size - fixed) / perBatch);
        if (chunk > B) chunk = B;

        // zero stats + cnt (offs region included, overwritten by scan anyway)
        hipMemsetAsync(ws, 0, 160512, stream);

        stats_kernel<<<256, 256, 0, stream>>>(ea, stats);
        finalize_kernel<<<1, 64, 0, stream>>>(stats);
        count_kernel<<<(E + 255) / 256, 256, 0, stream>>>(eidx, cnt);
        scan_kernel<<<1, 1024, 0, stream>>>(cnt, offs, cnt);
        fill_kernel<<<(E + 255) / 256, 256, 0, stream>>>(eidx, cnt, lists);

        for (int b0 = 0; b0 < B; b0 += chunk) {
            int nb = B - b0; if (nb > chunk) nb = chunk;
            int nwork = nb * E;
            edge_mlp_kernel<<<(nwork + 255) / 256, 256, 0, stream>>>(
                x, eidx, ea, wind_mean, wind_std, W1, b1, W2, b2, stats,
                eBuf, b0, nb);
            gather_kernel<<<nb * (N * 64 / 256), 256, 0, stream>>>(
                eBuf, offs, lists, Wn, bn, out, b0, nb);
        }
    } else {
        // fallback: atomic scatter path (round 1)
        float* agg = (float*)(ws + 256);
        size_t zero_bytes = 256 + (size_t)B * N * EOUT * sizeof(float);
        hipMemsetAsync(ws, 0, zero_bytes, stream);
        stats_kernel<<<256, 256, 0, stream>>>(ea, stats);
        finalize_kernel<<<1, 64, 0, stream>>>(stats);
        int nwork = B * E;
        edge_kernel_atomic<<<(nwork + 255) / 256, 256, 0, stream>>>(
            x, eidx, ea, wind_mean, wind_std, W1, b1, W2, b2, stats, agg);
        int nout_elems = B * N * NOUT;
        node_kernel_fallback<<<(nout_elems + 255) / 256, 256, 0, stream>>>(
            agg, Wn, bn, out);
    }
}